// Round 1
// baseline (356.302 us; speedup 1.0000x reference)
//
#include <hip/hip_runtime.h>
#include <hip/hip_bf16.h>

#define S_LEN 1024
#define DIN 4096
#define NH 32
#define NG 8
#define HD 128

typedef __bf16 bf16x8 __attribute__((ext_vector_type(8)));
typedef __bf16 bf16x4 __attribute__((ext_vector_type(4)));
typedef float f32x4 __attribute__((ext_vector_type(4)));

__device__ __forceinline__ void gload_lds16(const void* g, void* l) {
  __builtin_amdgcn_global_load_lds(
      (const __attribute__((address_space(1))) unsigned int*)g,
      (__attribute__((address_space(3))) unsigned int*)l, 16, 0, 0);
}

__device__ __forceinline__ unsigned pack2bf(float a, float b) {
  union { __bf16 h[2]; unsigned u; } x;
  x.h[0] = (__bf16)a; x.h[1] = (__bf16)b;
  return x.u;
}

// ---------------- cast x: f32 -> bf16 ----------------
__global__ __launch_bounds__(256) void k_cast(const float* __restrict__ in,
                                              __bf16* __restrict__ out, int n4) {
  int i = blockIdx.x * 256 + threadIdx.x;
  if (i >= n4) return;
  const float4 v = ((const float4*)in)[i];
  bf16x4 o;
  o.x = (__bf16)v.x; o.y = (__bf16)v.y; o.z = (__bf16)v.z; o.w = (__bf16)v.w;
  ((bf16x4*)out)[i] = o;
}

// ---------------- transpose+cast: W (K,N) f32 -> WT (N,K) bf16 ----------------
__global__ __launch_bounds__(256) void k_transpose_cast(const float* __restrict__ W,
                                                        __bf16* __restrict__ WT,
                                                        int N, int K) {
  __shared__ __bf16 t[64][80];  // stride 160B: 16B-aligned rows, 8-bank shift/row
  const int tid = threadIdx.x;
  const int k0 = blockIdx.y * 64, n0 = blockIdx.x * 64;
#pragma unroll
  for (int p = 0; p < 4; ++p) {
    int kk = p * 16 + (tid >> 4);
    int nn = (tid & 15) * 4;
    const float4 v = *(const float4*)&W[(size_t)(k0 + kk) * N + n0 + nn];
    t[nn + 0][kk] = (__bf16)v.x;
    t[nn + 1][kk] = (__bf16)v.y;
    t[nn + 2][kk] = (__bf16)v.z;
    t[nn + 3][kk] = (__bf16)v.w;
  }
  __syncthreads();
#pragma unroll
  for (int p = 0; p < 2; ++p) {
    int nn = p * 32 + (tid >> 3);
    int kk = (tid & 7) * 8;
    bf16x8 v = *(const bf16x8*)&t[nn][kk];
    *(bf16x8*)&WT[(size_t)(n0 + nn) * K + k0 + kk] = v;
  }
}

// ---------------- RoPE in-place on Q (NH heads) and K (NG heads) ----------------
__global__ __launch_bounds__(256) void k_rope(__bf16* __restrict__ Q, __bf16* __restrict__ Kb,
                                              const float* __restrict__ cosT,
                                              const float* __restrict__ sinT) {
  int idx = blockIdx.x * 256 + threadIdx.x;
  const int QP = S_LEN * NH * 64;
  __bf16* t; int nh;
  if (idx < QP) { t = Q; nh = NH; }
  else {
    idx -= QP; t = Kb; nh = NG;
    if (idx >= S_LEN * NG * 64) return;
  }
  int d = idx & 63;
  int h = (idx >> 6) % nh;
  int s = idx / (64 * nh);
  float c = cosT[s * HD + d], sn = sinT[s * HD + d];
  size_t base = (size_t)s * nh * HD + h * HD + d;
  float t1 = (float)t[base], t2 = (float)t[base + 64];
  t[base]      = (__bf16)(t1 * c - t2 * sn);
  t[base + 64] = (__bf16)(t2 * c + t1 * sn);
}

// ---------------- m97-style GEMM: C(M,N) = A(M,K) * Bt(N,K)^T ----------------
template <typename OutT>
__device__ __forceinline__ void gemm_bt_body(const __bf16* __restrict__ A,
                                             const __bf16* __restrict__ Bt,
                                             OutT* __restrict__ C, int N, int K,
                                             __bf16* As, __bf16* Bs, int bm, int bn) {
  const int tid = threadIdx.x, w = tid >> 6, l = tid & 63;
  const int l15 = l & 15, g4 = l >> 4;
  const int mbase = (w >> 1) * 64, nbase = (w & 1) * 64;
  f32x4 acc[4][4];
#pragma unroll
  for (int i = 0; i < 4; ++i)
#pragma unroll
    for (int j = 0; j < 4; ++j)
#pragma unroll
      for (int r = 0; r < 4; ++r) acc[i][j][r] = 0.f;

  const int c0 = tid, c1 = 256 + tid;
  const int m0 = c0 >> 2, k80 = c0 & 3, m1 = c1 >> 2, k81 = c1 & 3;

  for (int k0 = 0; k0 < K; k0 += 32) {
    // stage A,B tiles (128x32 bf16 each) with chunk-XOR swizzle via global source
    gload_lds16(&A[(size_t)(bm * 128 + m0) * K + k0 + ((k80 ^ (m0 & 3)) << 3)], &As[(w * 64) * 8]);
    gload_lds16(&A[(size_t)(bm * 128 + m1) * K + k0 + ((k81 ^ (m1 & 3)) << 3)], &As[(256 + w * 64) * 8]);
    gload_lds16(&Bt[(size_t)(bn * 128 + m0) * K + k0 + ((k80 ^ (m0 & 3)) << 3)], &Bs[(w * 64) * 8]);
    gload_lds16(&Bt[(size_t)(bn * 128 + m1) * K + k0 + ((k81 ^ (m1 & 3)) << 3)], &Bs[(256 + w * 64) * 8]);
    __syncthreads();
    bf16x8 af[4], bfr[4];
#pragma unroll
    for (int i = 0; i < 4; ++i) {
      int m = mbase + i * 16 + l15;
      af[i] = *(const bf16x8*)((const char*)As + m * 64 + ((g4 ^ (m & 3)) << 4));
      int n = nbase + i * 16 + l15;
      bfr[i] = *(const bf16x8*)((const char*)Bs + n * 64 + ((g4 ^ (n & 3)) << 4));
    }
#pragma unroll
    for (int i = 0; i < 4; ++i)
#pragma unroll
      for (int j = 0; j < 4; ++j)
        acc[i][j] = __builtin_amdgcn_mfma_f32_16x16x32_bf16(af[i], bfr[j], acc[i][j], 0, 0, 0);
    __syncthreads();
  }
#pragma unroll
  for (int i = 0; i < 4; ++i)
#pragma unroll
    for (int j = 0; j < 4; ++j)
#pragma unroll
      for (int r = 0; r < 4; ++r) {
        size_t row = bm * 128 + mbase + i * 16 + g4 * 4 + r;
        size_t col = bn * 128 + nbase + j * 16 + l15;
        C[row * N + col] = (OutT)acc[i][j][r];
      }
}

template <typename OutT>
__global__ __launch_bounds__(256) void k_gemm_bt(const __bf16* __restrict__ A,
                                                 const __bf16* __restrict__ Bt,
                                                 OutT* __restrict__ C, int N, int K) {
  __shared__ __bf16 As[128 * 32], Bs[128 * 32];
  gemm_bt_body<OutT>(A, Bt, C, N, K, As, Bs, blockIdx.y, blockIdx.x);
}

__global__ __launch_bounds__(256) void k_gemm_bt_dual(const __bf16* A0, const __bf16* B0, __bf16* C0,
                                                      const __bf16* A1, const __bf16* B1, __bf16* C1,
                                                      int N, int K) {
  __shared__ __bf16 As[128 * 32], Bs[128 * 32];
  if (blockIdx.z == 0) gemm_bt_body<__bf16>(A0, B0, C0, N, K, As, Bs, blockIdx.y, blockIdx.x);
  else                 gemm_bt_body<__bf16>(A1, B1, C1, N, K, As, Bs, blockIdx.y, blockIdx.x);
}

// ---------------- flash attention ----------------
// grid (S/64, NH). 4 waves x 16 q-rows. BKV=128. Swapped QK^T; online softmax.
// LDS 64KB: Ks[128][128] | Vs[128][128]; P regions alias the (dead) Ks after QK^T.
__global__ __launch_bounds__(256) void k_attn(const __bf16* __restrict__ Q,
                                              const __bf16* __restrict__ Kb,
                                              const __bf16* __restrict__ Vt,
                                              __bf16* __restrict__ ctx) {
  __shared__ __align__(16) char lds_raw[65536];
  __bf16* Ks = (__bf16*)lds_raw;
  __bf16* Vs = (__bf16*)(lds_raw + 32768);

  const int h = blockIdx.y, g = h >> 2;
  const int q0 = blockIdx.x * 64;
  const int tid = threadIdx.x, w = tid >> 6, l = tid & 63;
  const int l15 = l & 15, g4 = l >> 4;
  const float scale = 0.08838834764831845f;  // 1/sqrt(128)

  bf16x8 qf[4];
  const int qrow = q0 + w * 16 + l15;
#pragma unroll
  for (int ks = 0; ks < 4; ++ks)
    qf[ks] = *(const bf16x8*)&Q[(size_t)qrow * (NH * HD) + h * HD + ks * 32 + g4 * 8];

  f32x4 acc[8];
#pragma unroll
  for (int i = 0; i < 8; ++i)
#pragma unroll
    for (int r = 0; r < 4; ++r) acc[i][r] = 0.f;
  float m_run = -__builtin_inff(), l_run = 0.f;

  const int ntiles = (q0 + 64 + 127) >> 7;
  for (int kt = 0; kt < ntiles; ++kt) {
    const int kv0 = kt * 128;
    // ---- stage K tile (Ks[t][d]) and V^T tile (Vs[d][t]), row-XOR-swizzled ----
#pragma unroll
    for (int p = 0; p < 8; ++p) {
      int c = p * 256 + tid;
      int row = c >> 4, cc = c & 15;
      gload_lds16(&Kb[(size_t)(kv0 + row) * (NG * HD) + g * HD + ((cc ^ (row & 7)) << 3)],
                  &Ks[(p * 256 + w * 64) * 8]);
      gload_lds16(&Vt[(size_t)(g * HD + row) * S_LEN + kv0 + ((cc ^ (row & 7)) << 3)],
                  &Vs[(p * 256 + w * 64) * 8]);
    }
    __syncthreads();

    // ---- swapped QK^T: sreg[tf][r] = S^T[t, q=l15] ----
    float sreg[8][4];
    const bool need_mask = (kv0 + 127 > q0);
#pragma unroll
    for (int tf = 0; tf < 8; ++tf) {
      f32x4 sa;
#pragma unroll
      for (int r = 0; r < 4; ++r) sa[r] = 0.f;
      int t_loc = tf * 16 + l15;
#pragma unroll
      for (int ks = 0; ks < 4; ++ks) {
        bf16x8 kf = *(const bf16x8*)((const char*)Ks + t_loc * 256 + (((ks * 4 + g4) ^ (t_loc & 7)) << 4));
        sa = __builtin_amdgcn_mfma_f32_16x16x32_bf16(kf, qf[ks], sa, 0, 0, 0);
      }
#pragma unroll
      for (int r = 0; r < 4; ++r) {
        float v = sa[r] * scale;
        if (need_mask && (kv0 + tf * 16 + g4 * 4 + r) > qrow) v = -__builtin_inff();
        sreg[tf][r] = v;
      }
    }
    // ---- online softmax for q = l15 (reduce over t: in-lane + lanes^16,^32) ----
    float mx = -__builtin_inff();
#pragma unroll
    for (int tf = 0; tf < 8; ++tf)
#pragma unroll
      for (int r = 0; r < 4; ++r) mx = fmaxf(mx, sreg[tf][r]);
    mx = fmaxf(mx, __shfl_xor(mx, 16));
    mx = fmaxf(mx, __shfl_xor(mx, 32));
    const float m_new = fmaxf(m_run, mx);
    const float alpha = __expf(m_run - m_new);
    float ssum = 0.f;
#pragma unroll
    for (int tf = 0; tf < 8; ++tf)
#pragma unroll
      for (int r = 0; r < 4; ++r) {
        sreg[tf][r] = __expf(sreg[tf][r] - m_new);
        ssum += sreg[tf][r];
      }
    ssum += __shfl_xor(ssum, 16);
    ssum += __shfl_xor(ssum, 32);
    l_run = l_run * alpha + ssum;
    m_run = m_new;
    // rescale ctx (rows q' = g4*4+r; alpha lives on lane q')
    float ar[4];
#pragma unroll
    for (int r = 0; r < 4; ++r) ar[r] = __shfl(alpha, g4 * 4 + r);
#pragma unroll
    for (int nf = 0; nf < 8; ++nf)
#pragma unroll
      for (int r = 0; r < 4; ++r) acc[nf][r] *= ar[r];

    __syncthreads();  // all waves done reading Ks; its region now holds P

    // ---- P -> LDS (per-wave 4KB region inside old Ks), bf16, swizzled ----
    char* pb = lds_raw + w * 4096;
#pragma unroll
    for (int tf = 0; tf < 8; ++tf) {
      int chunkc = 2 * tf + (g4 >> 1);
      int addr = l15 * 256 + ((chunkc ^ (l15 & 7)) << 4) + ((g4 & 1) << 3);
      *(unsigned*)(pb + addr)     = pack2bf(sreg[tf][0], sreg[tf][1]);
      *(unsigned*)(pb + addr + 4) = pack2bf(sreg[tf][2], sreg[tf][3]);
    }
    asm volatile("s_waitcnt lgkmcnt(0)" ::: "memory");
    // ---- PV: ctx[q, d] += P(16x128) * V(128x128) ----
    bf16x8 pf[4];
#pragma unroll
    for (int ks = 0; ks < 4; ++ks)
      pf[ks] = *(const bf16x8*)(pb + l15 * 256 + (((ks * 4 + g4) ^ (l15 & 7)) << 4));
#pragma unroll
    for (int nf = 0; nf < 8; ++nf) {
      int d_loc = nf * 16 + l15;
#pragma unroll
      for (int ks = 0; ks < 4; ++ks) {
        bf16x8 vf = *(const bf16x8*)((const char*)Vs + d_loc * 256 + (((ks * 4 + g4) ^ (d_loc & 7)) << 4));
        acc[nf] = __builtin_amdgcn_mfma_f32_16x16x32_bf16(pf[ks], vf, acc[nf], 0, 0, 0);
      }
    }
    __syncthreads();
  }
  // ---- epilogue: normalize and store ctx[s, h*128+d] bf16 ----
  float li[4];
#pragma unroll
  for (int r = 0; r < 4; ++r) li[r] = 1.f / __shfl(l_run, g4 * 4 + r);
#pragma unroll
  for (int nf = 0; nf < 8; ++nf)
#pragma unroll
    for (int r = 0; r < 4; ++r) {
      size_t row = q0 + w * 16 + g4 * 4 + r;
      size_t col = (size_t)h * HD + nf * 16 + l15;
      ctx[row * (NH * HD) + col] = (__bf16)(acc[nf][r] * li[r]);
    }
}

// ---------------- host ----------------
extern "C" void kernel_launch(void* const* d_in, const int* in_sizes, int n_in,
                              void* d_out, int out_size, void* d_ws, size_t ws_size,
                              hipStream_t stream) {
  const float* x    = (const float*)d_in[0];
  const float* cosT = (const float*)d_in[2];
  const float* sinT = (const float*)d_in[3];
  const float* Wq   = (const float*)d_in[4];
  const float* Wk   = (const float*)d_in[5];
  const float* Wv   = (const float*)d_in[6];
  const float* Wo   = (const float*)d_in[7];
  float* out = (float*)d_out;

  char* ws = (char*)d_ws;
  const size_t MB = 1u << 20;
  __bf16* xb   = (__bf16*)(ws + 0);        // 8 MB  : x bf16 (1024 x 4096)
  __bf16* WqT  = (__bf16*)(ws + 8 * MB);   // 32 MB : Wq^T (4096 x 4096)
  __bf16* WkT  = (__bf16*)(ws + 40 * MB);  // 8 MB  : Wk^T (1024 x 4096)
  __bf16* WvT  = (__bf16*)(ws + 48 * MB);  // 8 MB  : Wv^T (1024 x 4096)
  __bf16* WoT  = (__bf16*)(ws + 56 * MB);  // 32 MB : Wo^T (4096 x 4096)
  __bf16* Qb   = (__bf16*)(ws + 88 * MB);  // 8 MB  : Q (1024 x 4096), roped in-place
  __bf16* Kbuf = (__bf16*)(ws + 96 * MB);  // 2 MB  : K (1024 x 1024), roped in-place
  __bf16* Vtb  = (__bf16*)(ws + 98 * MB);  // 2 MB  : V^T (1024 x 1024)
  __bf16* ctxb = (__bf16*)(ws + 100 * MB); // 8 MB  : attention output (1024 x 4096)

  k_cast<<<4096, 256, 0, stream>>>(x, xb, (S_LEN * DIN) / 4);
  k_transpose_cast<<<dim3(64, 64), 256, 0, stream>>>(Wq, WqT, 4096, 4096);
  k_transpose_cast<<<dim3(16, 64), 256, 0, stream>>>(Wk, WkT, 1024, 4096);
  k_transpose_cast<<<dim3(16, 64), 256, 0, stream>>>(Wv, WvT, 1024, 4096);
  k_transpose_cast<<<dim3(64, 64), 256, 0, stream>>>(Wo, WoT, 4096, 4096);

  // Q = xb * WqT^T  (1024 x 4096)
  k_gemm_bt<__bf16><<<dim3(32, 8), 256, 0, stream>>>(xb, WqT, Qb, 4096, 4096);
  // K = xb * WkT^T  and  V^T = WvT * xb^T  (both 1024 x 1024), fused launch
  k_gemm_bt_dual<<<dim3(8, 8, 2), 256, 0, stream>>>(xb, WkT, Kbuf, WvT, xb, Vtb, 1024, 4096);

  k_rope<<<10240, 256, 0, stream>>>(Qb, Kbuf, cosT, sinT);

  k_attn<<<dim3(16, 32), 256, 0, stream>>>(Qb, Kbuf, Vtb, ctxb);

  // out = ctx * WoT^T  (1024 x 4096), f32
  k_gemm_bt<float><<<dim3(32, 8), 256, 0, stream>>>(ctxb, WoT, out, 4096, 4096);
}

// Round 2
// 223.229 us; speedup vs baseline: 1.5961x; 1.5961x over previous
//
#include <hip/hip_runtime.h>
#include <hip/hip_bf16.h>

#define S_LEN 1024
#define DIN 4096
#define NH 32
#define NG 8
#define HD 128

typedef __bf16 bf16x8 __attribute__((ext_vector_type(8)));
typedef __bf16 bf16x4 __attribute__((ext_vector_type(4)));
typedef float f32x4 __attribute__((ext_vector_type(4)));

__device__ __forceinline__ void gload_lds16(const void* g, void* l) {
  __builtin_amdgcn_global_load_lds(
      (const __attribute__((address_space(1))) unsigned int*)g,
      (__attribute__((address_space(3))) unsigned int*)l, 16, 0, 0);
}

__device__ __forceinline__ unsigned pack2bf(float a, float b) {
  union { __bf16 h[2]; unsigned u; } x;
  x.h[0] = (__bf16)a; x.h[1] = (__bf16)b;
  return x.u;
}

// ---------------- cast x: f32 -> bf16 ----------------
__global__ __launch_bounds__(256) void k_cast(const float* __restrict__ in,
                                              __bf16* __restrict__ out, int n4) {
  int i = blockIdx.x * 256 + threadIdx.x;
  if (i >= n4) return;
  const float4 v = ((const float4*)in)[i];
  bf16x4 o;
  o.x = (__bf16)v.x; o.y = (__bf16)v.y; o.z = (__bf16)v.z; o.w = (__bf16)v.w;
  ((bf16x4*)out)[i] = o;
}

// ---------------- transpose+cast: W (K,N) f32 -> WT (N,K) bf16 ----------------
__global__ __launch_bounds__(256) void k_transpose_cast(const float* __restrict__ W,
                                                        __bf16* __restrict__ WT,
                                                        int N, int K) {
  __shared__ __bf16 t[64][80];
  const int tid = threadIdx.x;
  const int k0 = blockIdx.y * 64, n0 = blockIdx.x * 64;
#pragma unroll
  for (int p = 0; p < 4; ++p) {
    int kk = p * 16 + (tid >> 4);
    int nn = (tid & 15) * 4;
    const float4 v = *(const float4*)&W[(size_t)(k0 + kk) * N + n0 + nn];
    t[nn + 0][kk] = (__bf16)v.x;
    t[nn + 1][kk] = (__bf16)v.y;
    t[nn + 2][kk] = (__bf16)v.z;
    t[nn + 3][kk] = (__bf16)v.w;
  }
  __syncthreads();
#pragma unroll
  for (int p = 0; p < 2; ++p) {
    int nn = p * 32 + (tid >> 3);
    int kk = (tid & 7) * 8;
    bf16x8 v = *(const bf16x8*)&t[nn][kk];
    *(bf16x8*)&WT[(size_t)(n0 + nn) * K + k0 + kk] = v;
  }
}

// ---------------- RoPE in-place on Q (NH heads) and K (NG heads) ----------------
__global__ __launch_bounds__(256) void k_rope(__bf16* __restrict__ Q, __bf16* __restrict__ Kb,
                                              const float* __restrict__ cosT,
                                              const float* __restrict__ sinT) {
  int idx = blockIdx.x * 256 + threadIdx.x;
  const int QP = S_LEN * NH * 64;
  __bf16* t; int nh;
  if (idx < QP) { t = Q; nh = NH; }
  else {
    idx -= QP; t = Kb; nh = NG;
    if (idx >= S_LEN * NG * 64) return;
  }
  int d = idx & 63;
  int h = (idx >> 6) % nh;
  int s = idx / (64 * nh);
  float c = cosT[s * HD + d], sn = sinT[s * HD + d];
  size_t base = (size_t)s * nh * HD + h * HD + d;
  float t1 = (float)t[base], t2 = (float)t[base + 64];
  t[base]      = (__bf16)(t1 * c - t2 * sn);
  t[base + 64] = (__bf16)(t2 * c + t1 * sn);
}

// ---------------- V (s,d) -> V^T (d,s), bf16 ----------------
__global__ __launch_bounds__(256) void k_vt(const __bf16* __restrict__ V,
                                            __bf16* __restrict__ Vt) {
  __shared__ __bf16 t[64][72];
  const int tid = threadIdx.x;
  const int s0 = blockIdx.y * 64, d0 = blockIdx.x * 64;
#pragma unroll
  for (int p = 0; p < 2; ++p) {
    int ss = p * 32 + (tid >> 3);
    int dd = (tid & 7) * 8;
    bf16x8 v = *(const bf16x8*)&V[(size_t)(s0 + ss) * 1024 + d0 + dd];
#pragma unroll
    for (int e = 0; e < 8; ++e) t[dd + e][ss] = v[e];
  }
  __syncthreads();
#pragma unroll
  for (int p = 0; p < 2; ++p) {
    int dd = p * 32 + (tid >> 3);
    int ss = (tid & 7) * 8;
    *(bf16x8*)&Vt[(size_t)(d0 + dd) * 1024 + s0 + ss] = *(const bf16x8*)&t[dd][ss];
  }
}

// ---------------- GEMM: C(M,N) = A(M,K) * Bt(N,K)^T ----------------
// BM=128, BN=64, BK=64. 4 waves, wave w owns rows [w*32, w*32+32).
// 3-bit XOR swizzle: LDS row r (128B) slot s holds global k-chunk s^(r&7).
// MODE 0: plain OutT output (ldN = N). MODE 1: QKV region-split bf16 epilogue.
template <int MODE, typename OutT>
__global__ __launch_bounds__(256, 3) void k_gemm(const __bf16* __restrict__ A,
                                                 const __bf16* __restrict__ Bt,
                                                 OutT* __restrict__ C, int N, int K,
                                                 __bf16* __restrict__ Qb,
                                                 __bf16* __restrict__ Kb,
                                                 __bf16* __restrict__ Vb) {
  __shared__ __bf16 As[128 * 64], Bs[64 * 64];
  const int bm = blockIdx.y, bn = blockIdx.x;
  const int tid = threadIdx.x, w = tid >> 6;
  const int l = tid & 63, l15 = l & 15, g4 = l >> 4;

  f32x4 acc[2][4];
#pragma unroll
  for (int i = 0; i < 2; ++i)
#pragma unroll
    for (int j = 0; j < 4; ++j)
#pragma unroll
      for (int r = 0; r < 4; ++r) acc[i][j][r] = 0.f;

  for (int k0 = 0; k0 < K; k0 += 64) {
    // stage A (128x64) and B (64x64) bf16 tiles, source pre-swizzled
#pragma unroll
    for (int p = 0; p < 4; ++p) {
      int c = p * 256 + tid;
      int row = c >> 3, gc = (c & 7) ^ (row & 7);
      gload_lds16(&A[(size_t)(bm * 128 + row) * K + k0 + gc * 8], &As[(p * 256 + w * 64) * 8]);
    }
#pragma unroll
    for (int p = 0; p < 2; ++p) {
      int c = p * 256 + tid;
      int row = c >> 3, gc = (c & 7) ^ (row & 7);
      gload_lds16(&Bt[(size_t)(bn * 64 + row) * K + k0 + gc * 8], &Bs[(p * 256 + w * 64) * 8]);
    }
    __syncthreads();

    bf16x8 af[2][2], bfr[4][2];
#pragma unroll
    for (int i = 0; i < 2; ++i) {
      int m = w * 32 + i * 16 + l15;
#pragma unroll
      for (int kk = 0; kk < 2; ++kk)
        af[i][kk] = *(const bf16x8*)((const char*)As + m * 128 + (((kk * 4 + g4) ^ (m & 7)) << 4));
    }
#pragma unroll
    for (int j = 0; j < 4; ++j) {
      int n = j * 16 + l15;
#pragma unroll
      for (int kk = 0; kk < 2; ++kk)
        bfr[j][kk] = *(const bf16x8*)((const char*)Bs + n * 128 + (((kk * 4 + g4) ^ (n & 7)) << 4));
    }
#pragma unroll
    for (int kk = 0; kk < 2; ++kk)
#pragma unroll
      for (int i = 0; i < 2; ++i)
#pragma unroll
        for (int j = 0; j < 4; ++j)
          acc[i][j] = __builtin_amdgcn_mfma_f32_16x16x32_bf16(af[i][kk], bfr[j][kk], acc[i][j], 0, 0, 0);
    __syncthreads();
  }

  if constexpr (MODE == 0) {
#pragma unroll
    for (int i = 0; i < 2; ++i)
#pragma unroll
      for (int j = 0; j < 4; ++j)
#pragma unroll
        for (int r = 0; r < 4; ++r) {
          size_t row = bm * 128 + w * 32 + i * 16 + g4 * 4 + r;
          size_t col = bn * 64 + j * 16 + l15;
          C[row * N + col] = (OutT)acc[i][j][r];
        }
  } else {
    // QKV split: cols [0,4096) -> Qb, [4096,5120) -> Kb, [5120,6144) -> Vb
    const int nb0 = bn * 64;
    __bf16* dst; int ldc, coff;
    if (nb0 < 4096)      { dst = Qb; ldc = 4096; coff = 0; }
    else if (nb0 < 5120) { dst = Kb; ldc = 1024; coff = 4096; }
    else                 { dst = Vb; ldc = 1024; coff = 5120; }
#pragma unroll
    for (int i = 0; i < 2; ++i)
#pragma unroll
      for (int j = 0; j < 4; ++j)
#pragma unroll
        for (int r = 0; r < 4; ++r) {
          size_t row = bm * 128 + w * 32 + i * 16 + g4 * 4 + r;
          size_t col = nb0 + j * 16 + l15 - coff;
          dst[row * ldc + col] = (__bf16)acc[i][j][r];
        }
  }
}

// ---------------- flash attention ----------------
// grid (S/64, NH). 4 waves x 16 q-rows. BKV=128. Swapped QK^T; online softmax.
__global__ __launch_bounds__(256) void k_attn(const __bf16* __restrict__ Q,
                                              const __bf16* __restrict__ Kb,
                                              const __bf16* __restrict__ Vt,
                                              __bf16* __restrict__ ctx) {
  __shared__ __align__(16) char lds_raw[65536];
  __bf16* Ks = (__bf16*)lds_raw;
  __bf16* Vs = (__bf16*)(lds_raw + 32768);

  const int h = blockIdx.y, g = h >> 2;
  const int q0 = blockIdx.x * 64;
  const int tid = threadIdx.x, w = tid >> 6, l = tid & 63;
  const int l15 = l & 15, g4 = l >> 4;
  const float scale = 0.08838834764831845f;  // 1/sqrt(128)

  bf16x8 qf[4];
  const int qrow = q0 + w * 16 + l15;
#pragma unroll
  for (int ks = 0; ks < 4; ++ks)
    qf[ks] = *(const bf16x8*)&Q[(size_t)qrow * (NH * HD) + h * HD + ks * 32 + g4 * 8];

  f32x4 acc[8];
#pragma unroll
  for (int i = 0; i < 8; ++i)
#pragma unroll
    for (int r = 0; r < 4; ++r) acc[i][r] = 0.f;
  float m_run = -__builtin_inff(), l_run = 0.f;

  const int ntiles = (q0 + 64 + 127) >> 7;
  for (int kt = 0; kt < ntiles; ++kt) {
    const int kv0 = kt * 128;
#pragma unroll
    for (int p = 0; p < 8; ++p) {
      int c = p * 256 + tid;
      int row = c >> 4, cc = c & 15;
      gload_lds16(&Kb[(size_t)(kv0 + row) * (NG * HD) + g * HD + ((cc ^ (row & 7)) << 3)],
                  &Ks[(p * 256 + w * 64) * 8]);
      gload_lds16(&Vt[(size_t)(g * HD + row) * S_LEN + kv0 + ((cc ^ (row & 7)) << 3)],
                  &Vs[(p * 256 + w * 64) * 8]);
    }
    __syncthreads();

    float sreg[8][4];
    const bool need_mask = (kv0 + 127 > q0);
#pragma unroll
    for (int tf = 0; tf < 8; ++tf) {
      f32x4 sa;
#pragma unroll
      for (int r = 0; r < 4; ++r) sa[r] = 0.f;
      int t_loc = tf * 16 + l15;
#pragma unroll
      for (int ks = 0; ks < 4; ++ks) {
        bf16x8 kf = *(const bf16x8*)((const char*)Ks + t_loc * 256 + (((ks * 4 + g4) ^ (t_loc & 7)) << 4));
        sa = __builtin_amdgcn_mfma_f32_16x16x32_bf16(kf, qf[ks], sa, 0, 0, 0);
      }
#pragma unroll
      for (int r = 0; r < 4; ++r) {
        float v = sa[r] * scale;
        if (need_mask && (kv0 + tf * 16 + g4 * 4 + r) > qrow) v = -__builtin_inff();
        sreg[tf][r] = v;
      }
    }
    float mx = -__builtin_inff();
#pragma unroll
    for (int tf = 0; tf < 8; ++tf)
#pragma unroll
      for (int r = 0; r < 4; ++r) mx = fmaxf(mx, sreg[tf][r]);
    mx = fmaxf(mx, __shfl_xor(mx, 16));
    mx = fmaxf(mx, __shfl_xor(mx, 32));
    const float m_new = fmaxf(m_run, mx);
    const float alpha = __expf(m_run - m_new);
    float ssum = 0.f;
#pragma unroll
    for (int tf = 0; tf < 8; ++tf)
#pragma unroll
      for (int r = 0; r < 4; ++r) {
        sreg[tf][r] = __expf(sreg[tf][r] - m_new);
        ssum += sreg[tf][r];
      }
    ssum += __shfl_xor(ssum, 16);
    ssum += __shfl_xor(ssum, 32);
    l_run = l_run * alpha + ssum;
    m_run = m_new;
    float ar[4];
#pragma unroll
    for (int r = 0; r < 4; ++r) ar[r] = __shfl(alpha, g4 * 4 + r);
#pragma unroll
    for (int nf = 0; nf < 8; ++nf)
#pragma unroll
      for (int r = 0; r < 4; ++r) acc[nf][r] *= ar[r];

    __syncthreads();

    char* pb = lds_raw + w * 4096;
#pragma unroll
    for (int tf = 0; tf < 8; ++tf) {
      int chunkc = 2 * tf + (g4 >> 1);
      int addr = l15 * 256 + ((chunkc ^ (l15 & 7)) << 4) + ((g4 & 1) << 3);
      *(unsigned*)(pb + addr)     = pack2bf(sreg[tf][0], sreg[tf][1]);
      *(unsigned*)(pb + addr + 4) = pack2bf(sreg[tf][2], sreg[tf][3]);
    }
    asm volatile("s_waitcnt lgkmcnt(0)" ::: "memory");
    bf16x8 pf[4];
#pragma unroll
    for (int ks = 0; ks < 4; ++ks)
      pf[ks] = *(const bf16x8*)(pb + l15 * 256 + (((ks * 4 + g4) ^ (l15 & 7)) << 4));
#pragma unroll
    for (int nf = 0; nf < 8; ++nf) {
      int d_loc = nf * 16 + l15;
#pragma unroll
      for (int ks = 0; ks < 4; ++ks) {
        bf16x8 vf = *(const bf16x8*)((const char*)Vs + d_loc * 256 + (((ks * 4 + g4) ^ (d_loc & 7)) << 4));
        acc[nf] = __builtin_amdgcn_mfma_f32_16x16x32_bf16(pf[ks], vf, acc[nf], 0, 0, 0);
      }
    }
    __syncthreads();
  }
  float li[4];
#pragma unroll
  for (int r = 0; r < 4; ++r) li[r] = 1.f / __shfl(l_run, g4 * 4 + r);
#pragma unroll
  for (int nf = 0; nf < 8; ++nf)
#pragma unroll
    for (int r = 0; r < 4; ++r) {
      size_t row = q0 + w * 16 + g4 * 4 + r;
      size_t col = (size_t)h * HD + nf * 16 + l15;
      ctx[row * (NH * HD) + col] = (__bf16)(acc[nf][r] * li[r]);
    }
}

// ---------------- host ----------------
extern "C" void kernel_launch(void* const* d_in, const int* in_sizes, int n_in,
                              void* d_out, int out_size, void* d_ws, size_t ws_size,
                              hipStream_t stream) {
  const float* x    = (const float*)d_in[0];
  const float* cosT = (const float*)d_in[2];
  const float* sinT = (const float*)d_in[3];
  const float* Wq   = (const float*)d_in[4];
  const float* Wk   = (const float*)d_in[5];
  const float* Wv   = (const float*)d_in[6];
  const float* Wo   = (const float*)d_in[7];
  float* out = (float*)d_out;

  char* ws = (char*)d_ws;
  const size_t MB = 1u << 20;
  __bf16* xb    = (__bf16*)(ws + 0);         // 8 MB : x bf16; reused as ctx after QKV GEMM
  __bf16* WqkvT = (__bf16*)(ws + 8 * MB);    // 48 MB: [Wq^T | Wk^T | Wv^T] (6144 x 4096)
  __bf16* WoT   = (__bf16*)(ws + 56 * MB);   // 32 MB: Wo^T (4096 x 4096)
  __bf16* Qb    = (__bf16*)(ws + 88 * MB);   // 8 MB : Q (1024 x 4096), roped in-place
  __bf16* Kbuf  = (__bf16*)(ws + 96 * MB);   // 2 MB : K (1024 x 1024), roped in-place
  __bf16* Vb    = (__bf16*)(ws + 98 * MB);   // 2 MB : V (1024 x 1024)
  __bf16* Vtb   = (__bf16*)(ws + 100 * MB);  // 2 MB : V^T (1024 x 1024)
  __bf16* ctxb  = (__bf16*)(ws + 0);         // aliases xb (dead after QKV GEMM)

  k_cast<<<4096, 256, 0, stream>>>(x, xb, (S_LEN * DIN) / 4);
  k_transpose_cast<<<dim3(64, 64), 256, 0, stream>>>(Wq, WqkvT, 4096, 4096);
  k_transpose_cast<<<dim3(16, 64), 256, 0, stream>>>(Wk, WqkvT + (size_t)4096 * 4096, 1024, 4096);
  k_transpose_cast<<<dim3(16, 64), 256, 0, stream>>>(Wv, WqkvT + (size_t)5120 * 4096, 1024, 4096);
  k_transpose_cast<<<dim3(64, 64), 256, 0, stream>>>(Wo, WoT, 4096, 4096);

  // fused QKV: (1024 x 6144) = xb (1024x4096) * WqkvT^T, region-split epilogue
  k_gemm<1, __bf16><<<dim3(96, 8), 256, 0, stream>>>(xb, WqkvT, (__bf16*)nullptr, 6144, 4096,
                                                     Qb, Kbuf, Vb);
  k_rope<<<10240, 256, 0, stream>>>(Qb, Kbuf, cosT, sinT);
  k_vt<<<dim3(16, 16), 256, 0, stream>>>(Vb, Vtb);

  k_attn<<<dim3(16, 32), 256, 0, stream>>>(Qb, Kbuf, Vtb, ctxb);

  // out = ctx * WoT^T (1024 x 4096), f32
  k_gemm<0, float><<<dim3(64, 8), 256, 0, stream>>>(ctxb, WoT, out, 4096, 4096,
                                                    nullptr, nullptr, nullptr);
}